// Round 1
// baseline (550.360 us; speedup 1.0000x reference)
//
#include <hip/hip_runtime.h>
#include <cstddef>

#define NB 4
#define NP 8192
#define NK 16
#define NC 128
#define HW_ 136   // center_k LDS stride (shorts): 272B rows, 16B-aligned
#define GIW 136   // stab gather/H stride (shorts): 272B rows; rel f32 tail @ +128
#define AGW 136
#define FSW 136
#define H2W 136

using short8   = __attribute__((ext_vector_type(8))) short;
using ushort4v = __attribute__((ext_vector_type(4))) unsigned short;
using floatx4  = __attribute__((ext_vector_type(4))) float;

__device__ __forceinline__ unsigned short f2bf(float f) {
    union { float f; unsigned u; } v; v.f = f;
    unsigned r = v.u + 0x7FFFu + ((v.u >> 16) & 1u);   // RNE
    return (unsigned short)(r >> 16);
}
__device__ __forceinline__ float bf2f(unsigned short u) {
    union { unsigned u; float f; } v; v.u = ((unsigned)u) << 16;
    return v.f;
}

#define MFMA(a, b, c) __builtin_amdgcn_mfma_f32_16x16x32_bf16((a), (b), (c), 0, 0, 0)

// ---------------------------------------------------------------------------
// Weight packing: fp32 -> bf16. edge_W1 feat-part (cols 3..130) packed as a
// dense 128x128 for the G-GEMM; rel-part (cols 0..2) is read raw fp32 in
// stab_iter_k. Total elems: 16384+49152+49152+98304+49152 = 262144.
// ---------------------------------------------------------------------------
__global__ void pack_weights_k(const float* __restrict__ offW1,
                               const float* __restrict__ eW1,
                               const float* __restrict__ eW2,
                               const float* __restrict__ uW1,
                               const float* __restrict__ uW2,
                               unsigned short* __restrict__ offW1p,
                               unsigned short* __restrict__ eW1fp,
                               unsigned short* __restrict__ eW2p,
                               unsigned short* __restrict__ uW1p,
                               unsigned short* __restrict__ uW2p)
{
    int i = blockIdx.x * 256 + threadIdx.x;
    if (i < 16384) { offW1p[i] = f2bf(offW1[i]); return; }
    i -= 16384;
    if (i < 49152) {
        int tt = i / 16384, rem = i % 16384;
        int o = rem / 128, k = rem % 128;
        eW1fp[i] = f2bf(eW1[(tt * 128 + o) * 131 + 3 + k]);
        return;
    }
    i -= 49152;
    if (i < 49152) { eW2p[i] = f2bf(eW2[i]); return; }
    i -= 49152;
    if (i < 98304) { uW1p[i] = f2bf(uW1[i]); return; }
    i -= 98304;
    if (i < 49152) { uW2p[i] = f2bf(uW2[i]); }
}

// ---------------------------------------------------------------------------
// center_k: 32 points/block (grid 1024). Offset MLP -> ctr, and the hoisted
// edge-L1 feat projection G = F @ W1f^T (bf16 out, no bias/relu — those are
// applied per-edge in stab_iter_k after adding the rel contribution).
// ---------------------------------------------------------------------------
__global__ __launch_bounds__(256, 4)
void center_k(const float* __restrict__ Fin, const float* __restrict__ xyz,
              const unsigned short* __restrict__ offW1p,
              const float* __restrict__ offW2, const float* __restrict__ offb1,
              const float* __restrict__ offb2,
              const unsigned short* __restrict__ eW1fp,
              unsigned short* __restrict__ Gbf, float* __restrict__ ctr)
{
    __shared__ __align__(16) unsigned short sA[32 * HW_];
    __shared__ __align__(16) unsigned short sH[32 * HW_];
    const int t = threadIdx.x, wv = t >> 6, ln = t & 63, q = ln >> 4, r = ln & 15;
    const int cg0 = wv << 1;
    const int base = blockIdx.x * 32;

    {   // 32x128 fp32 -> bf16 -> sA
        int row = t >> 3, c16 = (t & 7) * 16;
        const float* src = Fin + (size_t)(base + row) * NC + c16;
        float4 f0 = *(const float4*)src;
        float4 f1 = *(const float4*)(src + 4);
        float4 f2 = *(const float4*)(src + 8);
        float4 f3 = *(const float4*)(src + 12);
        short8 u0, u1;
        u0[0]=f2bf(f0.x); u0[1]=f2bf(f0.y); u0[2]=f2bf(f0.z); u0[3]=f2bf(f0.w);
        u0[4]=f2bf(f1.x); u0[5]=f2bf(f1.y); u0[6]=f2bf(f1.z); u0[7]=f2bf(f1.w);
        u1[0]=f2bf(f2.x); u1[1]=f2bf(f2.y); u1[2]=f2bf(f2.z); u1[3]=f2bf(f2.w);
        u1[4]=f2bf(f3.x); u1[5]=f2bf(f3.y); u1[6]=f2bf(f3.z); u1[7]=f2bf(f3.w);
        *(short8*)&sA[row * HW_ + c16]     = u0;
        *(short8*)&sA[row * HW_ + c16 + 8] = u1;
    }
    __syncthreads();

    {   // offset L1 + G-GEMM, 2 row-tiles x 2 col-tiles per wave
        short8 wo[2][4], wg[2][4];
#pragma unroll
        for (int c = 0; c < 2; ++c)
#pragma unroll
            for (int ks = 0; ks < 4; ++ks) {
                wo[c][ks] = *(const short8*)(offW1p + ((cg0 + c) * 16 + r) * NC + ks * 32 + q * 8);
                wg[c][ks] = *(const short8*)(eW1fp  + ((cg0 + c) * 16 + r) * NC + ks * 32 + q * 8);
            }
        float bo[2] = { offb1[cg0 * 16 + r], offb1[(cg0 + 1) * 16 + r] };
#pragma unroll
        for (int rt = 0; rt < 2; ++rt) {
            short8 af[4];
#pragma unroll
            for (int ks = 0; ks < 4; ++ks)
                af[ks] = *(const short8*)&sA[(rt * 16 + r) * HW_ + ks * 32 + q * 8];
            floatx4 ao[2] = { {0.f,0.f,0.f,0.f}, {0.f,0.f,0.f,0.f} };
            floatx4 ag[2] = { {0.f,0.f,0.f,0.f}, {0.f,0.f,0.f,0.f} };
#pragma unroll
            for (int c = 0; c < 2; ++c)
#pragma unroll
                for (int ks = 0; ks < 4; ++ks) {
                    ao[c] = MFMA(af[ks], wo[c][ks], ao[c]);
                    ag[c] = MFMA(af[ks], wg[c][ks], ag[c]);
                }
#pragma unroll
            for (int c = 0; c < 2; ++c) {
                int col = (cg0 + c) * 16 + r;
#pragma unroll
                for (int i = 0; i < 4; ++i) {
                    int row = rt * 16 + q * 4 + i;
                    sH[row * HW_ + col] = f2bf(fmaxf(ao[c][i] + bo[c], 0.f));
                    Gbf[(size_t)(base + row) * NC + col] = f2bf(ag[c][i]);
                }
            }
        }
    }
    __syncthreads();

    if (wv < 2) {   // offset L2 (out=3, zero-padded cols), one row-tile per wave
        int rt = wv;
        short8 wf[4];
#pragma unroll
        for (int ks = 0; ks < 4; ++ks) {
            short8 u = {0,0,0,0,0,0,0,0};
            if (r < 3) {
                const float* w = offW2 + r * NC + ks * 32 + q * 8;
                float4 f0 = *(const float4*)w;
                float4 f1 = *(const float4*)(w + 4);
                u[0]=f2bf(f0.x); u[1]=f2bf(f0.y); u[2]=f2bf(f0.z); u[3]=f2bf(f0.w);
                u[4]=f2bf(f1.x); u[5]=f2bf(f1.y); u[6]=f2bf(f1.z); u[7]=f2bf(f1.w);
            }
            wf[ks] = u;
        }
        short8 af[4];
#pragma unroll
        for (int ks = 0; ks < 4; ++ks)
            af[ks] = *(const short8*)&sH[(rt * 16 + r) * HW_ + ks * 32 + q * 8];
        floatx4 acc = {0.f, 0.f, 0.f, 0.f};
#pragma unroll
        for (int ks = 0; ks < 4; ++ks)
            acc = MFMA(af[ks], wf[ks], acc);
        if (r < 3) {
#pragma unroll
            for (int i = 0; i < 4; ++i) {
                int p = rt * 16 + q * 4 + i;
                ctr[(size_t)(base + p) * 3 + r] =
                    xyz[(size_t)(base + p) * 3 + r] + acc[i] + offb2[r];
            }
        }
    }
}

// ---------------------------------------------------------------------------
// Fused iteration: gather G -> in-place L1' (G + W1r·rel + b, relu) ->
// edge L2 MFMA -> max(K) -> update MLP -> residual.
// 256 thr / 4 waves / 8 points. LDS 26048 B -> 6 blocks/CU.
// Half-1 gather prefetched into regs (issued after first barrier, lands
// after half-0 L2). Barriers: 7 (was 10).
// ---------------------------------------------------------------------------
__global__ __launch_bounds__(256, 6)
void stab_iter_k(const float* __restrict__ Fin, float* __restrict__ Fout,
                 const unsigned short* __restrict__ Gbf,
                 const float* __restrict__ xyz, const int* __restrict__ knn,
                 const float* __restrict__ ctr,
                 const float* __restrict__ eW1r,   // raw edge_W1 + t*128*131
                 const float* __restrict__ eb1, const float* __restrict__ eb2,
                 const unsigned short* __restrict__ eW2p,
                 const unsigned short* __restrict__ uW1p,
                 const unsigned short* __restrict__ uW2p,
                 const float* __restrict__ ub1, const float* __restrict__ ub2)
{
    __shared__ __align__(16) unsigned short s_GI[64 * GIW];   // 17408 B; H2 aliases
    __shared__ __align__(16) unsigned short s_AGG[16 * AGW];  // 4352 B (rows 8..15 garbage, row-local safe)
    __shared__ __align__(16) unsigned short s_FSB[8 * FSW];   // 2176 B  self features bf16
    __shared__ __align__(16) float s_W1R[4 * 132];            // 2112 B  rows 0-2: W1rel[j][col]; row 3: eb1

    unsigned short* H2 = s_GI;

    // XCD swizzle: batch b -> XCDs {2b, 2b+1} (L2 locality for G gathers)
    const int xcd  = blockIdx.x & 7;
    const int slot = blockIdx.x >> 3;
    const int b    = xcd >> 1;
    const int n0   = ((slot << 1) | (xcd & 1)) << 3;
    const int t = threadIdx.x, wv = t >> 6, ln = t & 63;
    const int q = ln >> 4, r = ln & 15, cg0 = wv << 1;
    const int base = b * NP + n0;
    const int rr = t >> 4, c8 = (t & 15) * 8;

    // ---- P0: knn, gather h0, rel (both halves), edge-L2 weights
    const int* kb = knn + (size_t)base * NK;
    int kn[8];
#pragma unroll
    for (int j = 0; j < 8; ++j) kn[j] = kb[j * 16 + rr];
    short8 g0[4];
#pragma unroll
    for (int p = 0; p < 4; ++p)
        g0[p] = *(const short8*)(Gbf + (size_t)(b * NP + kn[p]) * NC + c8);
    float rel0[3] = {0.f,0.f,0.f}, rel1[3] = {0.f,0.f,0.f};
    if (t < 64) {
        int nb0 = kb[t], nb1 = kb[64 + t];
        const float* x0  = xyz + (size_t)(b * NP + nb0) * 3;
        const float* x1  = xyz + (size_t)(b * NP + nb1) * 3;
        const float* c0p = ctr + (size_t)(base + (t >> 4)) * 3;
        const float* c1p = ctr + (size_t)(base + 4 + (t >> 4)) * 3;
#pragma unroll
        for (int j = 0; j < 3; ++j) { rel0[j] = x0[j] - c0p[j]; rel1[j] = x1[j] - c1p[j]; }
    }
    short8 wf2[2][4];
#pragma unroll
    for (int c = 0; c < 2; ++c)
#pragma unroll
        for (int ks = 0; ks < 4; ++ks)
            wf2[c][ks] = *(const short8*)(eW2p + ((cg0 + c) * 16 + r) * NC + ks * 32 + q * 8);
    float eb2v[2] = { eb2[cg0 * 16 + r], eb2[(cg0 + 1) * 16 + r] };

    // ---- P1: stage LDS
    {
        int row = t >> 5, c4 = (t & 31) * 4;
        float4 f = *(const float4*)(Fin + (size_t)(base + row) * NC + c4);
        ushort4v u = { f2bf(f.x), f2bf(f.y), f2bf(f.z), f2bf(f.w) };
        *(ushort4v*)&s_FSB[row * FSW + c4] = u;
    }
    if (t < 128) {
        int j = t >> 5, c0 = (t & 31) * 4;
#pragma unroll
        for (int k = 0; k < 4; ++k)
            s_W1R[j * 132 + c0 + k] = (j < 3) ? eW1r[(c0 + k) * 131 + j] : eb1[c0 + k];
    }
#pragma unroll
    for (int p = 0; p < 4; ++p)
        *(short8*)&s_GI[(p * 16 + rr) * GIW + c8] = g0[p];
    if (t < 64) {
        float* relp = (float*)&s_GI[t * GIW + 128];
        relp[0] = rel0[0]; relp[1] = rel0[1]; relp[2] = rel0[2];
    }
    __syncthreads();

    // prefetch half-1 gather (flies under the in-place pass + L2 phase)
    short8 g1[4];
#pragma unroll
    for (int p = 0; p < 4; ++p)
        g1[p] = *(const short8*)(Gbf + (size_t)(b * NP + kn[4 + p]) * NC + c8);

#pragma unroll
    for (int h = 0; h < 2; ++h) {
        // ---- in-place edge L1': H = relu(G + W1r·rel + b1), vectorized b128
        {
            const int erow = t >> 2, ec0 = (t & 3) * 32;
            const float* relp = (const float*)&s_GI[erow * GIW + 128];
            float rl0 = relp[0], rl1 = relp[1], rl2 = relp[2];
#pragma unroll
            for (int g = 0; g < 4; ++g) {
                int c0 = ec0 + g * 8;
                short8 gv = *(short8*)&s_GI[erow * GIW + c0];
                floatx4 w0a = *(const floatx4*)&s_W1R[0 * 132 + c0];
                floatx4 w0b = *(const floatx4*)&s_W1R[0 * 132 + c0 + 4];
                floatx4 w1a = *(const floatx4*)&s_W1R[1 * 132 + c0];
                floatx4 w1b = *(const floatx4*)&s_W1R[1 * 132 + c0 + 4];
                floatx4 w2a = *(const floatx4*)&s_W1R[2 * 132 + c0];
                floatx4 w2b = *(const floatx4*)&s_W1R[2 * 132 + c0 + 4];
                floatx4 bba = *(const floatx4*)&s_W1R[3 * 132 + c0];
                floatx4 bbb = *(const floatx4*)&s_W1R[3 * 132 + c0 + 4];
                short8 hv;
#pragma unroll
                for (int e = 0; e < 4; ++e) {
                    float ha = bf2f((unsigned short)gv[e]) + bba[e];
                    ha = fmaf(w0a[e], rl0, ha);
                    ha = fmaf(w1a[e], rl1, ha);
                    ha = fmaf(w2a[e], rl2, ha);
                    hv[e] = (short)f2bf(fmaxf(ha, 0.f));
                    float hb = bf2f((unsigned short)gv[e + 4]) + bbb[e];
                    hb = fmaf(w0b[e], rl0, hb);
                    hb = fmaf(w1b[e], rl1, hb);
                    hb = fmaf(w2b[e], rl2, hb);
                    hv[e + 4] = (short)f2bf(fmaxf(hb, 0.f));
                }
                *(short8*)&s_GI[erow * GIW + c0] = hv;
            }
        }
        __syncthreads();

        // ---- edge L2 + max over K (16-row tile = one point)
#pragma unroll
        for (int rt = 0; rt < 4; ++rt) {
            short8 af[4];
#pragma unroll
            for (int ks = 0; ks < 4; ++ks)
                af[ks] = *(const short8*)&s_GI[(rt * 16 + r) * GIW + ks * 32 + q * 8];
            floatx4 acc[2] = { {0.f,0.f,0.f,0.f}, {0.f,0.f,0.f,0.f} };
#pragma unroll
            for (int c = 0; c < 2; ++c)
#pragma unroll
                for (int ks = 0; ks < 4; ++ks)
                    acc[c] = MFMA(af[ks], wf2[c][ks], acc[c]);
#pragma unroll
            for (int c = 0; c < 2; ++c) {
                float m = fmaxf(fmaxf(acc[c][0], acc[c][1]), fmaxf(acc[c][2], acc[c][3]));
                m = fmaxf(m, __shfl_xor(m, 16));
                m = fmaxf(m, __shfl_xor(m, 32));
                if (q == 0)
                    s_AGG[(h * 4 + rt) * AGW + (cg0 + c) * 16 + r] = f2bf(m + eb2v[c]);
            }
        }
        __syncthreads();

        if (h == 0) {   // write prefetched half-1 gather
#pragma unroll
            for (int p = 0; p < 4; ++p)
                *(short8*)&s_GI[(p * 16 + rr) * GIW + c8] = g1[p];
            if (t < 64) {
                float* relp = (float*)&s_GI[t * GIW + 128];
                relp[0] = rel1[0]; relp[1] = rel1[1]; relp[2] = rel1[2];
            }
            __syncthreads();
        }
    }

    // ---- update L1: [agg | self] (K=256) -> H2 (aliases s_GI)
    {
        short8 wfa[2][8];
#pragma unroll
        for (int c = 0; c < 2; ++c)
#pragma unroll
            for (int ks = 0; ks < 8; ++ks)
                wfa[c][ks] = *(const short8*)(uW1p + ((cg0 + c) * 16 + r) * 256 + ks * 32 + q * 8);
        short8 af[8];
#pragma unroll
        for (int ks = 0; ks < 4; ++ks)
            af[ks] = *(const short8*)&s_AGG[r * AGW + ks * 32 + q * 8];
#pragma unroll
        for (int ks = 0; ks < 4; ++ks)
            af[4 + ks] = *(const short8*)&s_FSB[(r & 7) * FSW + ks * 32 + q * 8];
        floatx4 acc3[2] = { {0.f,0.f,0.f,0.f}, {0.f,0.f,0.f,0.f} };
#pragma unroll
        for (int c = 0; c < 2; ++c)
#pragma unroll
            for (int ks = 0; ks < 8; ++ks)
                acc3[c] = MFMA(af[ks], wfa[c][ks], acc3[c]);
#pragma unroll
        for (int c = 0; c < 2; ++c) {
            int col = (cg0 + c) * 16 + r;
            float bv = ub1[col];
#pragma unroll
            for (int i = 0; i < 4; ++i)
                H2[(q * 4 + i) * H2W + col] = f2bf(fmaxf(acc3[c][i] + bv, 0.f));
        }
    }
    __syncthreads();

    // ---- update L2 + residual -> Fout
    {
        short8 wfb[2][4];
#pragma unroll
        for (int c = 0; c < 2; ++c)
#pragma unroll
            for (int ks = 0; ks < 4; ++ks)
                wfb[c][ks] = *(const short8*)(uW2p + ((cg0 + c) * 16 + r) * NC + ks * 32 + q * 8);
        short8 af[4];
#pragma unroll
        for (int ks = 0; ks < 4; ++ks)
            af[ks] = *(const short8*)&H2[r * H2W + ks * 32 + q * 8];
        floatx4 acc[2] = { {0.f,0.f,0.f,0.f}, {0.f,0.f,0.f,0.f} };
#pragma unroll
        for (int c = 0; c < 2; ++c)
#pragma unroll
            for (int ks = 0; ks < 4; ++ks)
                acc[c] = MFMA(af[ks], wfb[c][ks], acc[c]);
        if (q < 2) {
#pragma unroll
            for (int c = 0; c < 2; ++c) {
                int col = (cg0 + c) * 16 + r;
                float bv = ub2[col];
#pragma unroll
                for (int i = 0; i < 4; ++i) {
                    int p = q * 4 + i;   // 0..7
                    size_t o = (size_t)(base + p) * NC + col;
                    Fout[o] = Fin[o] + acc[c][i] + bv;
                }
            }
        }
    }
}

// ---------------------------------------------------------------------------
extern "C" void kernel_launch(void* const* d_in, const int* in_sizes, int n_in,
                              void* d_out, int out_size, void* d_ws, size_t ws_size,
                              hipStream_t stream)
{
    const float* xyz   = (const float*)d_in[0];
    const float* feat  = (const float*)d_in[1];
    const int*   knn   = (const int*)d_in[2];
    const float* offW1 = (const float*)d_in[3];
    const float* offb1 = (const float*)d_in[4];
    const float* offW2 = (const float*)d_in[5];
    const float* offb2 = (const float*)d_in[6];
    const float* eW1   = (const float*)d_in[7];
    const float* eb1   = (const float*)d_in[8];
    const float* eW2   = (const float*)d_in[9];
    const float* eb2   = (const float*)d_in[10];
    const float* uW1   = (const float*)d_in[11];
    const float* ub1   = (const float*)d_in[12];
    const float* uW2   = (const float*)d_in[13];
    const float* ub2   = (const float*)d_in[14];
    float* out = (float*)d_out;

    char* ws = (char*)d_ws;
    unsigned short* Gbf    = (unsigned short*)ws;                 // 8388608 B
    float*          ctrb   = (float*)(ws + 8388608);              // 393216 B
    unsigned short* offW1p = (unsigned short*)(ws + 8781824);     // 32768 B
    unsigned short* eW1fp  = (unsigned short*)(ws + 8814592);     // 98304 B
    unsigned short* eW2p   = (unsigned short*)(ws + 8912896);     // 98304 B
    unsigned short* uW1p   = (unsigned short*)(ws + 9011200);     // 196608 B
    unsigned short* uW2p   = (unsigned short*)(ws + 9207808);     // 98304 B

    pack_weights_k<<<1024, 256, 0, stream>>>(offW1, eW1, eW2, uW1, uW2,
                                             offW1p, eW1fp, eW2p, uW1p, uW2p);

    const float* fin[3] = { feat, out, out };
    for (int tt = 0; tt < 3; ++tt) {
        center_k<<<1024, 256, 0, stream>>>(fin[tt], xyz, offW1p, offW2,
                                           offb1, offb2, eW1fp + tt * 16384,
                                           Gbf, ctrb);
        stab_iter_k<<<4096, 256, 0, stream>>>(
            fin[tt], out, Gbf, xyz, knn, ctrb,
            eW1 + tt * 128 * 131, eb1 + tt * 128, eb2 + tt * 128,
            eW2p + tt * 16384, uW1p + tt * 32768, uW2p + tt * 16384,
            ub1 + tt * 128, ub2 + tt * 128);
    }
}

// Round 2
// 409.678 us; speedup vs baseline: 1.3434x; 1.3434x over previous
//
#include <hip/hip_runtime.h>
#include <cstddef>

#define NB 4
#define NP 8192
#define NK 16
#define NC 128
#define HW_ 136   // center_k LDS stride (shorts): 272B rows, 16B-aligned
#define GIW 136   // stab gather/H stride (shorts): 272B rows; rel f32 tail @ +128
#define AGW 136
#define FSW 136
#define H2W 136

using short8   = __attribute__((ext_vector_type(8))) short;
using ushort4v = __attribute__((ext_vector_type(4))) unsigned short;
using floatx4  = __attribute__((ext_vector_type(4))) float;

__device__ __forceinline__ unsigned short f2bf(float f) {
    union { float f; unsigned u; } v; v.f = f;
    unsigned r = v.u + 0x7FFFu + ((v.u >> 16) & 1u);   // RNE
    return (unsigned short)(r >> 16);
}
__device__ __forceinline__ float bf2f(unsigned short u) {
    union { unsigned u; float f; } v; v.u = ((unsigned)u) << 16;
    return v.f;
}

#define MFMA(a, b, c) __builtin_amdgcn_mfma_f32_16x16x32_bf16((a), (b), (c), 0, 0, 0)

// ---------------------------------------------------------------------------
// Weight packing: fp32 -> bf16. edge_W1 feat-part (cols 3..130) packed as a
// dense 128x128 for the G-GEMM; rel-part (cols 0..2) is read raw fp32 in
// stab_iter_k. Total elems: 16384+49152+49152+98304+49152 = 262144.
// ---------------------------------------------------------------------------
__global__ void pack_weights_k(const float* __restrict__ offW1,
                               const float* __restrict__ eW1,
                               const float* __restrict__ eW2,
                               const float* __restrict__ uW1,
                               const float* __restrict__ uW2,
                               unsigned short* __restrict__ offW1p,
                               unsigned short* __restrict__ eW1fp,
                               unsigned short* __restrict__ eW2p,
                               unsigned short* __restrict__ uW1p,
                               unsigned short* __restrict__ uW2p)
{
    int i = blockIdx.x * 256 + threadIdx.x;
    if (i < 16384) { offW1p[i] = f2bf(offW1[i]); return; }
    i -= 16384;
    if (i < 49152) {
        int tt = i / 16384, rem = i % 16384;
        int o = rem / 128, k = rem % 128;
        eW1fp[i] = f2bf(eW1[(tt * 128 + o) * 131 + 3 + k]);
        return;
    }
    i -= 49152;
    if (i < 49152) { eW2p[i] = f2bf(eW2[i]); return; }
    i -= 49152;
    if (i < 98304) { uW1p[i] = f2bf(uW1[i]); return; }
    i -= 98304;
    if (i < 49152) { uW2p[i] = f2bf(uW2[i]); }
}

// ---------------------------------------------------------------------------
// center_k: 32 points/block (grid 1024). Offset MLP -> ctr, and the hoisted
// edge-L1 feat projection G = F @ W1f^T (bf16 out, no bias/relu — those are
// applied per-edge in stab_iter_k after adding the rel contribution).
// ---------------------------------------------------------------------------
__global__ __launch_bounds__(256, 4)
void center_k(const float* __restrict__ Fin, const float* __restrict__ xyz,
              const unsigned short* __restrict__ offW1p,
              const float* __restrict__ offW2, const float* __restrict__ offb1,
              const float* __restrict__ offb2,
              const unsigned short* __restrict__ eW1fp,
              unsigned short* __restrict__ Gbf, float* __restrict__ ctr)
{
    __shared__ __align__(16) unsigned short sA[32 * HW_];
    __shared__ __align__(16) unsigned short sH[32 * HW_];
    const int t = threadIdx.x, wv = t >> 6, ln = t & 63, q = ln >> 4, r = ln & 15;
    const int cg0 = wv << 1;
    const int base = blockIdx.x * 32;

    {   // 32x128 fp32 -> bf16 -> sA
        int row = t >> 3, c16 = (t & 7) * 16;
        const float* src = Fin + (size_t)(base + row) * NC + c16;
        float4 f0 = *(const float4*)src;
        float4 f1 = *(const float4*)(src + 4);
        float4 f2 = *(const float4*)(src + 8);
        float4 f3 = *(const float4*)(src + 12);
        short8 u0, u1;
        u0[0]=f2bf(f0.x); u0[1]=f2bf(f0.y); u0[2]=f2bf(f0.z); u0[3]=f2bf(f0.w);
        u0[4]=f2bf(f1.x); u0[5]=f2bf(f1.y); u0[6]=f2bf(f1.z); u0[7]=f2bf(f1.w);
        u1[0]=f2bf(f2.x); u1[1]=f2bf(f2.y); u1[2]=f2bf(f2.z); u1[3]=f2bf(f2.w);
        u1[4]=f2bf(f3.x); u1[5]=f2bf(f3.y); u1[6]=f2bf(f3.z); u1[7]=f2bf(f3.w);
        *(short8*)&sA[row * HW_ + c16]     = u0;
        *(short8*)&sA[row * HW_ + c16 + 8] = u1;
    }
    __syncthreads();

    {   // offset L1 + G-GEMM, 2 row-tiles x 2 col-tiles per wave
        short8 wo[2][4], wg[2][4];
#pragma unroll
        for (int c = 0; c < 2; ++c)
#pragma unroll
            for (int ks = 0; ks < 4; ++ks) {
                wo[c][ks] = *(const short8*)(offW1p + ((cg0 + c) * 16 + r) * NC + ks * 32 + q * 8);
                wg[c][ks] = *(const short8*)(eW1fp  + ((cg0 + c) * 16 + r) * NC + ks * 32 + q * 8);
            }
        float bo[2] = { offb1[cg0 * 16 + r], offb1[(cg0 + 1) * 16 + r] };
#pragma unroll
        for (int rt = 0; rt < 2; ++rt) {
            short8 af[4];
#pragma unroll
            for (int ks = 0; ks < 4; ++ks)
                af[ks] = *(const short8*)&sA[(rt * 16 + r) * HW_ + ks * 32 + q * 8];
            floatx4 ao[2] = { {0.f,0.f,0.f,0.f}, {0.f,0.f,0.f,0.f} };
            floatx4 ag[2] = { {0.f,0.f,0.f,0.f}, {0.f,0.f,0.f,0.f} };
#pragma unroll
            for (int c = 0; c < 2; ++c)
#pragma unroll
                for (int ks = 0; ks < 4; ++ks) {
                    ao[c] = MFMA(af[ks], wo[c][ks], ao[c]);
                    ag[c] = MFMA(af[ks], wg[c][ks], ag[c]);
                }
#pragma unroll
            for (int c = 0; c < 2; ++c) {
                int col = (cg0 + c) * 16 + r;
#pragma unroll
                for (int i = 0; i < 4; ++i) {
                    int row = rt * 16 + q * 4 + i;
                    sH[row * HW_ + col] = f2bf(fmaxf(ao[c][i] + bo[c], 0.f));
                    Gbf[(size_t)(base + row) * NC + col] = f2bf(ag[c][i]);
                }
            }
        }
    }
    __syncthreads();

    if (wv < 2) {   // offset L2 (out=3, zero-padded cols), one row-tile per wave
        int rt = wv;
        short8 wf[4];
#pragma unroll
        for (int ks = 0; ks < 4; ++ks) {
            short8 u = {0,0,0,0,0,0,0,0};
            if (r < 3) {
                const float* w = offW2 + r * NC + ks * 32 + q * 8;
                float4 f0 = *(const float4*)w;
                float4 f1 = *(const float4*)(w + 4);
                u[0]=f2bf(f0.x); u[1]=f2bf(f0.y); u[2]=f2bf(f0.z); u[3]=f2bf(f0.w);
                u[4]=f2bf(f1.x); u[5]=f2bf(f1.y); u[6]=f2bf(f1.z); u[7]=f2bf(f1.w);
            }
            wf[ks] = u;
        }
        short8 af[4];
#pragma unroll
        for (int ks = 0; ks < 4; ++ks)
            af[ks] = *(const short8*)&sH[(rt * 16 + r) * HW_ + ks * 32 + q * 8];
        floatx4 acc = {0.f, 0.f, 0.f, 0.f};
#pragma unroll
        for (int ks = 0; ks < 4; ++ks)
            acc = MFMA(af[ks], wf[ks], acc);
        if (r < 3) {
#pragma unroll
            for (int i = 0; i < 4; ++i) {
                int p = rt * 16 + q * 4 + i;
                ctr[(size_t)(base + p) * 3 + r] =
                    xyz[(size_t)(base + p) * 3 + r] + acc[i] + offb2[r];
            }
        }
    }
}

// ---------------------------------------------------------------------------
// Fused iteration: gather G -> in-place L1' (G + W1r·rel + b, relu) ->
// edge L2 MFMA -> max(K) -> update MLP -> residual.
// 256 thr / 4 waves / 8 points. LDS 26048 B.
// __launch_bounds__(256,4): 128-VGPR cap. (256,6) in the previous round
// capped VGPRs at ~85 and SPILLED ~25 regs -> +190 MB scratch HBM traffic,
// 148 us. Natural pressure here is ~80-100; if it lands <=85 the LDS
// footprint still allows 6 blocks/CU.
// ---------------------------------------------------------------------------
__global__ __launch_bounds__(256, 4)
void stab_iter_k(const float* __restrict__ Fin, float* __restrict__ Fout,
                 const unsigned short* __restrict__ Gbf,
                 const float* __restrict__ xyz, const int* __restrict__ knn,
                 const float* __restrict__ ctr,
                 const float* __restrict__ eW1r,   // raw edge_W1 + t*128*131
                 const float* __restrict__ eb1, const float* __restrict__ eb2,
                 const unsigned short* __restrict__ eW2p,
                 const unsigned short* __restrict__ uW1p,
                 const unsigned short* __restrict__ uW2p,
                 const float* __restrict__ ub1, const float* __restrict__ ub2)
{
    __shared__ __align__(16) unsigned short s_GI[64 * GIW];   // 17408 B; H2 aliases
    __shared__ __align__(16) unsigned short s_AGG[16 * AGW];  // 4352 B (rows 8..15 garbage, row-local safe)
    __shared__ __align__(16) unsigned short s_FSB[8 * FSW];   // 2176 B  self features bf16
    __shared__ __align__(16) float s_W1R[4 * 132];            // 2112 B  rows 0-2: W1rel[j][col]; row 3: eb1

    unsigned short* H2 = s_GI;

    // XCD swizzle: batch b -> XCDs {2b, 2b+1} (L2 locality for G gathers)
    const int xcd  = blockIdx.x & 7;
    const int slot = blockIdx.x >> 3;
    const int b    = xcd >> 1;
    const int n0   = ((slot << 1) | (xcd & 1)) << 3;
    const int t = threadIdx.x, wv = t >> 6, ln = t & 63;
    const int q = ln >> 4, r = ln & 15, cg0 = wv << 1;
    const int base = b * NP + n0;
    const int rr = t >> 4, c8 = (t & 15) * 8;

    // ---- P0: knn, gather h0, rel (both halves), edge-L2 weights
    const int* kb = knn + (size_t)base * NK;
    int kn[8];
#pragma unroll
    for (int j = 0; j < 8; ++j) kn[j] = kb[j * 16 + rr];
    short8 g0[4];
#pragma unroll
    for (int p = 0; p < 4; ++p)
        g0[p] = *(const short8*)(Gbf + (size_t)(b * NP + kn[p]) * NC + c8);
    float rel0[3] = {0.f,0.f,0.f}, rel1[3] = {0.f,0.f,0.f};
    if (t < 64) {
        int nb0 = kb[t], nb1 = kb[64 + t];
        const float* x0  = xyz + (size_t)(b * NP + nb0) * 3;
        const float* x1  = xyz + (size_t)(b * NP + nb1) * 3;
        const float* c0p = ctr + (size_t)(base + (t >> 4)) * 3;
        const float* c1p = ctr + (size_t)(base + 4 + (t >> 4)) * 3;
#pragma unroll
        for (int j = 0; j < 3; ++j) { rel0[j] = x0[j] - c0p[j]; rel1[j] = x1[j] - c1p[j]; }
    }
    short8 wf2[2][4];
#pragma unroll
    for (int c = 0; c < 2; ++c)
#pragma unroll
        for (int ks = 0; ks < 4; ++ks)
            wf2[c][ks] = *(const short8*)(eW2p + ((cg0 + c) * 16 + r) * NC + ks * 32 + q * 8);
    float eb2v[2] = { eb2[cg0 * 16 + r], eb2[(cg0 + 1) * 16 + r] };

    // ---- P1: stage LDS
    {
        int row = t >> 5, c4 = (t & 31) * 4;
        float4 f = *(const float4*)(Fin + (size_t)(base + row) * NC + c4);
        ushort4v u = { f2bf(f.x), f2bf(f.y), f2bf(f.z), f2bf(f.w) };
        *(ushort4v*)&s_FSB[row * FSW + c4] = u;
    }
    if (t < 128) {
        int j = t >> 5, c0 = (t & 31) * 4;
#pragma unroll
        for (int k = 0; k < 4; ++k)
            s_W1R[j * 132 + c0 + k] = (j < 3) ? eW1r[(c0 + k) * 131 + j] : eb1[c0 + k];
    }
#pragma unroll
    for (int p = 0; p < 4; ++p)
        *(short8*)&s_GI[(p * 16 + rr) * GIW + c8] = g0[p];
    if (t < 64) {
        float* relp = (float*)&s_GI[t * GIW + 128];
        relp[0] = rel0[0]; relp[1] = rel0[1]; relp[2] = rel0[2];
    }
    __syncthreads();

    // prefetch half-1 gather (flies under the in-place pass + L2 phase)
    short8 g1[4];
#pragma unroll
    for (int p = 0; p < 4; ++p)
        g1[p] = *(const short8*)(Gbf + (size_t)(b * NP + kn[4 + p]) * NC + c8);

#pragma unroll
    for (int h = 0; h < 2; ++h) {
        // ---- in-place edge L1': H = relu(G + W1r·rel + b1), vectorized b128
        {
            const int erow = t >> 2, ec0 = (t & 3) * 32;
            const float* relp = (const float*)&s_GI[erow * GIW + 128];
            float rl0 = relp[0], rl1 = relp[1], rl2 = relp[2];
#pragma unroll
            for (int g = 0; g < 4; ++g) {
                int c0 = ec0 + g * 8;
                short8 gv = *(short8*)&s_GI[erow * GIW + c0];
                floatx4 w0a = *(const floatx4*)&s_W1R[0 * 132 + c0];
                floatx4 w0b = *(const floatx4*)&s_W1R[0 * 132 + c0 + 4];
                floatx4 w1a = *(const floatx4*)&s_W1R[1 * 132 + c0];
                floatx4 w1b = *(const floatx4*)&s_W1R[1 * 132 + c0 + 4];
                floatx4 w2a = *(const floatx4*)&s_W1R[2 * 132 + c0];
                floatx4 w2b = *(const floatx4*)&s_W1R[2 * 132 + c0 + 4];
                floatx4 bba = *(const floatx4*)&s_W1R[3 * 132 + c0];
                floatx4 bbb = *(const floatx4*)&s_W1R[3 * 132 + c0 + 4];
                short8 hv;
#pragma unroll
                for (int e = 0; e < 4; ++e) {
                    float ha = bf2f((unsigned short)gv[e]) + bba[e];
                    ha = fmaf(w0a[e], rl0, ha);
                    ha = fmaf(w1a[e], rl1, ha);
                    ha = fmaf(w2a[e], rl2, ha);
                    hv[e] = (short)f2bf(fmaxf(ha, 0.f));
                    float hb = bf2f((unsigned short)gv[e + 4]) + bbb[e];
                    hb = fmaf(w0b[e], rl0, hb);
                    hb = fmaf(w1b[e], rl1, hb);
                    hb = fmaf(w2b[e], rl2, hb);
                    hv[e + 4] = (short)f2bf(fmaxf(hb, 0.f));
                }
                *(short8*)&s_GI[erow * GIW + c0] = hv;
            }
        }
        __syncthreads();

        // ---- edge L2 + max over K (16-row tile = one point)
#pragma unroll
        for (int rt = 0; rt < 4; ++rt) {
            short8 af[4];
#pragma unroll
            for (int ks = 0; ks < 4; ++ks)
                af[ks] = *(const short8*)&s_GI[(rt * 16 + r) * GIW + ks * 32 + q * 8];
            floatx4 acc[2] = { {0.f,0.f,0.f,0.f}, {0.f,0.f,0.f,0.f} };
#pragma unroll
            for (int c = 0; c < 2; ++c)
#pragma unroll
                for (int ks = 0; ks < 4; ++ks)
                    acc[c] = MFMA(af[ks], wf2[c][ks], acc[c]);
#pragma unroll
            for (int c = 0; c < 2; ++c) {
                float m = fmaxf(fmaxf(acc[c][0], acc[c][1]), fmaxf(acc[c][2], acc[c][3]));
                m = fmaxf(m, __shfl_xor(m, 16));
                m = fmaxf(m, __shfl_xor(m, 32));
                if (q == 0)
                    s_AGG[(h * 4 + rt) * AGW + (cg0 + c) * 16 + r] = f2bf(m + eb2v[c]);
            }
        }
        __syncthreads();

        if (h == 0) {   // write prefetched half-1 gather
#pragma unroll
            for (int p = 0; p < 4; ++p)
                *(short8*)&s_GI[(p * 16 + rr) * GIW + c8] = g1[p];
            if (t < 64) {
                float* relp = (float*)&s_GI[t * GIW + 128];
                relp[0] = rel1[0]; relp[1] = rel1[1]; relp[2] = rel1[2];
            }
            __syncthreads();
        }
    }

    // ---- update L1: [agg | self] (K=256) -> H2 (aliases s_GI)
    {
        short8 wfa[2][8];
#pragma unroll
        for (int c = 0; c < 2; ++c)
#pragma unroll
            for (int ks = 0; ks < 8; ++ks)
                wfa[c][ks] = *(const short8*)(uW1p + ((cg0 + c) * 16 + r) * 256 + ks * 32 + q * 8);
        short8 af[8];
#pragma unroll
        for (int ks = 0; ks < 4; ++ks)
            af[ks] = *(const short8*)&s_AGG[r * AGW + ks * 32 + q * 8];
#pragma unroll
        for (int ks = 0; ks < 4; ++ks)
            af[4 + ks] = *(const short8*)&s_FSB[(r & 7) * FSW + ks * 32 + q * 8];
        floatx4 acc3[2] = { {0.f,0.f,0.f,0.f}, {0.f,0.f,0.f,0.f} };
#pragma unroll
        for (int c = 0; c < 2; ++c)
#pragma unroll
            for (int ks = 0; ks < 8; ++ks)
                acc3[c] = MFMA(af[ks], wfa[c][ks], acc3[c]);
#pragma unroll
        for (int c = 0; c < 2; ++c) {
            int col = (cg0 + c) * 16 + r;
            float bv = ub1[col];
#pragma unroll
            for (int i = 0; i < 4; ++i)
                H2[(q * 4 + i) * H2W + col] = f2bf(fmaxf(acc3[c][i] + bv, 0.f));
        }
    }
    __syncthreads();

    // ---- update L2 + residual -> Fout
    {
        short8 wfb[2][4];
#pragma unroll
        for (int c = 0; c < 2; ++c)
#pragma unroll
            for (int ks = 0; ks < 4; ++ks)
                wfb[c][ks] = *(const short8*)(uW2p + ((cg0 + c) * 16 + r) * NC + ks * 32 + q * 8);
        short8 af[4];
#pragma unroll
        for (int ks = 0; ks < 4; ++ks)
            af[ks] = *(const short8*)&H2[r * H2W + ks * 32 + q * 8];
        floatx4 acc[2] = { {0.f,0.f,0.f,0.f}, {0.f,0.f,0.f,0.f} };
#pragma unroll
        for (int c = 0; c < 2; ++c)
#pragma unroll
            for (int ks = 0; ks < 4; ++ks)
                acc[c] = MFMA(af[ks], wfb[c][ks], acc[c]);
        if (q < 2) {
#pragma unroll
            for (int c = 0; c < 2; ++c) {
                int col = (cg0 + c) * 16 + r;
                float bv = ub2[col];
#pragma unroll
                for (int i = 0; i < 4; ++i) {
                    int p = q * 4 + i;   // 0..7
                    size_t o = (size_t)(base + p) * NC + col;
                    Fout[o] = Fin[o] + acc[c][i] + bv;
                }
            }
        }
    }
}

// ---------------------------------------------------------------------------
extern "C" void kernel_launch(void* const* d_in, const int* in_sizes, int n_in,
                              void* d_out, int out_size, void* d_ws, size_t ws_size,
                              hipStream_t stream)
{
    const float* xyz   = (const float*)d_in[0];
    const float* feat  = (const float*)d_in[1];
    const int*   knn   = (const int*)d_in[2];
    const float* offW1 = (const float*)d_in[3];
    const float* offb1 = (const float*)d_in[4];
    const float* offW2 = (const float*)d_in[5];
    const float* offb2 = (const float*)d_in[6];
    const float* eW1   = (const float*)d_in[7];
    const float* eb1   = (const float*)d_in[8];
    const float* eW2   = (const float*)d_in[9];
    const float* eb2   = (const float*)d_in[10];
    const float* uW1   = (const float*)d_in[11];
    const float* ub1   = (const float*)d_in[12];
    const float* uW2   = (const float*)d_in[13];
    const float* ub2   = (const float*)d_in[14];
    float* out = (float*)d_out;

    char* ws = (char*)d_ws;
    unsigned short* Gbf    = (unsigned short*)ws;                 // 8388608 B
    float*          ctrb   = (float*)(ws + 8388608);              // 393216 B
    unsigned short* offW1p = (unsigned short*)(ws + 8781824);     // 32768 B
    unsigned short* eW1fp  = (unsigned short*)(ws + 8814592);     // 98304 B
    unsigned short* eW2p   = (unsigned short*)(ws + 8912896);     // 98304 B
    unsigned short* uW1p   = (unsigned short*)(ws + 9011200);     // 196608 B
    unsigned short* uW2p   = (unsigned short*)(ws + 9207808);     // 98304 B

    pack_weights_k<<<1024, 256, 0, stream>>>(offW1, eW1, eW2, uW1, uW2,
                                             offW1p, eW1fp, eW2p, uW1p, uW2p);

    const float* fin[3] = { feat, out, out };
    for (int tt = 0; tt < 3; ++tt) {
        center_k<<<1024, 256, 0, stream>>>(fin[tt], xyz, offW1p, offW2,
                                           offb1, offb2, eW1fp + tt * 16384,
                                           Gbf, ctrb);
        stab_iter_k<<<4096, 256, 0, stream>>>(
            fin[tt], out, Gbf, xyz, knn, ctrb,
            eW1 + tt * 128 * 131, eb1 + tt * 128, eb2 + tt * 128,
            eW2p + tt * 16384, uW1p + tt * 32768, uW2p + tt * 16384,
            ub1 + tt * 128, ub2 + tt * 128);
    }
}